// Round 13
// baseline (239.562 us; speedup 1.0000x reference)
//
#include <hip/hip_runtime.h>
#include <hip/hip_bf16.h>
#include <math.h>

#define BB   4
#define SS   2048
#define INF_ 256
#define EMB  512
#define NH   8
#define HD   64
#define NT   8192

typedef unsigned short u16;
typedef unsigned int   u32;
typedef __attribute__((ext_vector_type(8))) short bf16x8;   // 8 bf16 = 4 VGPRs
typedef __attribute__((ext_vector_type(8))) unsigned short u16x8;
typedef __attribute__((ext_vector_type(4))) float f32x4;

constexpr float C2  = 0.06375871607f;    // (1/sqrt(512)) * log2(e)
constexpr float TB  = 1.00390625f;       // 1 + 2^-8
constexpr float EPS = 1e-5f;

__device__ __forceinline__ u16 f2bf(float v) {
    __hip_bfloat16 h = __float2bfloat16(v);
    return *(u16*)&h;
}
__device__ __forceinline__ float bf2f(u16 u) {
    __hip_bfloat16 h = *(__hip_bfloat16*)&u;
    return __bfloat162float(h);
}
__device__ __forceinline__ u16 ftrunc_bf(float v) {     // trunc + half-ulp bias
    return (u16)(__float_as_uint(v * TB) >> 16);
}
__device__ __forceinline__ f32x4 mfma16(bf16x8 a, bf16x8 b, f32x4 c) {
    return __builtin_amdgcn_mfma_f32_16x16x32_bf16(a, b, c, 0, 0, 0);
}
__device__ __forceinline__ void async16(const void* g, void* l) {
    __builtin_amdgcn_global_load_lds(
        (const __attribute__((address_space(1))) void*)g,
        (__attribute__((address_space(3))) void*)l, 16, 0, 0);
}
__device__ __forceinline__ int derive_flag(const u16* x) {
    const int lane = threadIdx.x & 63;
    const unsigned e = (x[lane * 2] >> 7) & 0xFF;
    float pl = (e == 0 || (e >= 110 && e <= 140)) ? 1.0f : 0.0f;
    #pragma unroll
    for (int o = 1; o < 64; o <<= 1) pl += __shfl_xor(pl, o);
    return pl < 32.0f;
}

// ---------------------------------------------------------------------------
// Fused prep: z 0..7 weight transpose W[K][M]->Wt[M][K] bf16; z=8 x->bf16;
// z=9 biases/ln params -> packed f32.
// ---------------------------------------------------------------------------
__global__ __launch_bounds__(256) void prep(
    const u16* __restrict__ xsrc,
    const void* w0, const void* w1, const void* w2, const void* w3,
    const void* w4, const void* w5, const void* w6, const void* w7,
    const void* p0, const void* p1, const void* p2, const void* p3,
    const void* p4, const void* p5, const void* p6, const void* p7,
    const void* p8, const void* p9, const void* p10, const void* p11,
    u16* __restrict__ xbf, u16* __restrict__ wt1, u16* __restrict__ wt2,
    u16* __restrict__ f1t, u16* __restrict__ f2t, float* __restrict__ small)
{
    const int isf = derive_flag(xsrc);
    const int z = blockIdx.z;
    const int tid = threadIdx.x;

    if (z < 8) {
        int K, M; const void* src; u16* dst;
        switch (z) {
            case 0: K=256;  M=512;  src=w0; dst=wt1;             break;
            case 1: K=256;  M=512;  src=w1; dst=wt1+512*256;     break;
            case 2: K=256;  M=512;  src=w2; dst=wt1+2*512*256;   break;
            case 3: K=512;  M=512;  src=w3; dst=wt2;             break;
            case 4: K=512;  M=512;  src=w4; dst=wt2+512*512;     break;
            case 5: K=512;  M=512;  src=w5; dst=wt2+2*512*512;   break;
            case 6: K=512;  M=1024; src=w6; dst=f1t;             break;
            default:K=1024; M=512;  src=w7; dst=f2t;             break;
        }
        const int m0 = blockIdx.x * 32, k0 = blockIdx.y * 32;
        if (m0 >= M || k0 >= K) return;
        __shared__ u16 t[32][33];
        const int tx = tid & 31, ty = tid >> 5;
        #pragma unroll
        for (int i = 0; i < 4; ++i) {
            const int kk = k0 + ty + i * 8;
            t[ty + i * 8][tx] = isf ? ftrunc_bf(((const float*)src)[(size_t)kk * M + m0 + tx])
                                    : ((const u16*)src)[(size_t)kk * M + m0 + tx];
        }
        __syncthreads();
        #pragma unroll
        for (int i = 0; i < 4; ++i) {
            const int mm = m0 + ty + i * 8;
            dst[(size_t)mm * K + k0 + tx] = t[tx][ty + i * 8];
        }
    } else if (z == 8) {
        const int bid = blockIdx.y * 32 + blockIdx.x;    // 0..1023
        const int base = bid * 2048 + tid * 8;
        if (isf) {
            #pragma unroll
            for (int j = 0; j < 8; ++j)
                xbf[base + j] = ftrunc_bf(((const float*)xsrc)[base + j]);
        } else {
            *(u16x8*)&xbf[base] = *(const u16x8*)&xsrc[base];
        }
    } else {
        const int bid = blockIdx.y * 32 + blockIdx.x;
        if (bid >= 28) return;
        const int e = bid * 256 + tid;
        int id, i;
        if (e < 3072)      { id = e >> 9;               i = e & 511;          }
        else if (e < 4096) { id = 6;                    i = e - 3072;         }
        else               { id = 7 + ((e - 4096) >> 9); i = (e - 4096) & 511; }
        const void* src;
        switch (id) {
            case 0: src = p0; break;  case 1: src = p1; break;
            case 2: src = p2; break;  case 3: src = p3; break;
            case 4: src = p4; break;  case 5: src = p5; break;
            case 6: src = p6; break;  case 7: src = p7; break;
            case 8: src = p8; break;  case 9: src = p9; break;
            case 10: src = p10; break; default: src = p11; break;
        }
        small[e] = isf ? ((const float*)src)[i] : bf2f(((const u16*)src)[i]);
    }
}

// ---------------------------------------------------------------------------
// MFMA GEMM, 64x64 tile (8 blocks/CU for latency hiding on short-K loops).
// Grid: x = row-tile (XCD-aligned A reuse), y = which*(M/64) + col-tile.
// 4 waves, each 32x32 (2x2 fragments). BK=64, XOR-swizzled LDS, w=16 async.
// SCALEK: which==1 output scaled by C2 (k only feeds attention).
// VOUT: which==2 written transposed to [B][H][HD][S] via LDS.
// Epilogue routes acc through LDS so global stores are u16x8-coalesced.
// ---------------------------------------------------------------------------
template <bool RELU, bool AWHICH, bool VOUT, bool SCALEK>
__global__ __launch_bounds__(256) void gemm64(
    const u16* __restrict__ Aall, const u16* __restrict__ Wtall,
    const float* __restrict__ ball, u16* __restrict__ out,
    u16* __restrict__ vtb, int N, int K, int M)
{
    __shared__ __align__(16) u16 sA[64 * 64];   // 8 KB
    __shared__ __align__(16) u16 sB[64 * 64];   // 8 KB (also epilogue spill)

    const int mtiles = M >> 6;
    const int which = blockIdx.y / mtiles;
    const int colb  = blockIdx.y % mtiles;
    const int row0 = blockIdx.x << 6, col0 = colb << 6;
    const u16* A  = Aall + (AWHICH ? (size_t)which * N * K : 0);
    const u16* Wt = Wtall + (size_t)which * M * K;
    const float* bias = ball + (size_t)which * M;

    const int tid = threadIdx.x;
    const int lane = tid & 63, w = tid >> 6;
    const int wrow = (w & 1) << 5, wcol = (w >> 1) << 5;
    const int c = lane & 15, quad = lane >> 4;

    const u16* ap[2]; const u16* bp[2];
    #pragma unroll
    for (int i = 0; i < 2; ++i) {
        const int raw = i * 256 + tid, r = raw >> 3, ch = (raw & 7) ^ (r & 7);
        ap[i] = A + (size_t)(row0 + r) * K + ch * 8;
        bp[i] = Wt + (size_t)(col0 + r) * K + ch * 8;
    }

    f32x4 acc[2][2] = {};

    for (int k0 = 0; k0 < K; k0 += 64) {
        __syncthreads();
        #pragma unroll
        for (int i = 0; i < 2; ++i) {
            async16(ap[i], (char*)sA + (i * 256 + tid) * 16);
            ap[i] += 64;
            async16(bp[i], (char*)sB + (i * 256 + tid) * 16);
            bp[i] += 64;
        }
        __syncthreads();

        #pragma unroll
        for (int kt = 0; kt < 2; ++kt) {
            bf16x8 af[2], bfr[2];
            #pragma unroll
            for (int rt = 0; rt < 2; ++rt) {
                const int r = wrow + rt * 16 + c;
                af[rt] = *(const bf16x8*)&sA[(r * 8 + ((kt * 4 + quad) ^ (r & 7))) * 8];
            }
            #pragma unroll
            for (int ct = 0; ct < 2; ++ct) {
                const int r = wcol + ct * 16 + c;
                bfr[ct] = *(const bf16x8*)&sB[(r * 8 + ((kt * 4 + quad) ^ (r & 7))) * 8];
            }
            #pragma unroll
            for (int rt = 0; rt < 2; ++rt)
                #pragma unroll
                for (int ct = 0; ct < 2; ++ct)
                    acc[rt][ct] = mfma16(af[rt], bfr[ct], acc[rt][ct]);
        }
    }

    if (VOUT && which == 2) {
        // transpose through LDS: sA[col][row], stride 72 (144B rows, 16B-aligned)
        __syncthreads();
        #pragma unroll
        for (int rt = 0; rt < 2; ++rt) {
            const int rowb = wrow + rt * 16 + quad * 4;
            #pragma unroll
            for (int ct = 0; ct < 2; ++ct) {
                const int col = wcol + ct * 16 + c;
                const float bb = bias[col0 + col];
                ushort4 pk;
                pk.x = ftrunc_bf(acc[rt][ct][0] + bb);
                pk.y = ftrunc_bf(acc[rt][ct][1] + bb);
                pk.z = ftrunc_bf(acc[rt][ct][2] + bb);
                pk.w = ftrunc_bf(acc[rt][ct][3] + bb);
                *(ushort4*)&sA[col * 72 + rowb] = pk;
            }
        }
        __syncthreads();
        const int dl = tid >> 2, part = tid & 3;         // 64 cols x 4 row-parts
        const int hg = (col0 + dl) >> 6, dd = (col0 + dl) & 63;
        const int bb = row0 >> 11, s0 = row0 & 2047;
        u16* dst = vtb + ((size_t)(bb * NH + hg) * HD + dd) * SS + s0 + part * 16;
        #pragma unroll
        for (int j = 0; j < 2; ++j)
            *(u16x8*)&dst[j * 8] = *(const u16x8*)&sA[dl * 72 + part * 16 + j * 8];
        return;
    }

    // row-major epilogue through LDS: sA[row][col], stride 72, then
    // u16x8-coalesced stores (128B per wave instead of 4x32B scatter).
    const float sc = (SCALEK && which == 1) ? C2 : 1.0f;
    const size_t outW = (size_t)which * N * M;
    __syncthreads();
    #pragma unroll
    for (int rt = 0; rt < 2; ++rt) {
        #pragma unroll
        for (int ct = 0; ct < 2; ++ct) {
            const int col = wcol + ct * 16 + c;
            const float bb = bias[col0 + col];
            #pragma unroll
            for (int i = 0; i < 4; ++i) {
                const int row = wrow + rt * 16 + quad * 4 + i;
                float v = (acc[rt][ct][i] + bb) * sc;
                if (RELU) v = fmaxf(v, 0.0f);
                sA[row * 72 + col] = ftrunc_bf(v);
            }
        }
    }
    __syncthreads();
    const int dl = tid >> 2, part = tid & 3;             // 64 rows x 4 col-parts
    u16* dst = out + outW + (size_t)(row0 + dl) * M + col0 + part * 16;
    #pragma unroll
    for (int j = 0; j < 2; ++j)
        *(u16x8*)&dst[j * 8] = *(const u16x8*)&sA[dl * 72 + part * 16 + j * 8];
}

// ---------------------------------------------------------------------------
// MFMA flash attention, in-block 2-way K-split + s_setprio (R8 structure),
// pairwise-unrolled main loop (R12). Merge phase is now symmetric: each
// group exports one fragment's partials and merges the other (g0 exports
// f=1/merges f=0; g1 exports f=0/merges f=1) — disjoint row sets, both
// groups active in both phases, IEEE-add commutativity keeps the result
// bit-identical to the one-sided merge.
// ---------------------------------------------------------------------------
__global__ __launch_bounds__(1024) void attn_mfma(
    const u16* __restrict__ q, const u16* __restrict__ k,
    const u16* __restrict__ vt, u16* __restrict__ ctx)
{
    __shared__ __align__(16) u16 sK[2][2][4096];   // [group][buf][64x64] 32 KB
    __shared__ __align__(16) u16 sV[2][2][4096];   // 32 KB
    __shared__ __align__(16) u16 sP[32][1024];     // [wave*2+frag][16x64] 64 KB

    const int tid = threadIdx.x;
    const int w16 = tid >> 6, lane = tid & 63;
    const int g = w16 >> 3, w = w16 & 7;           // group, wave-in-group
    const int c = lane & 15, quad = lane >> 4;
    // XCD swizzle: id&7 = xcd; 32 slots/XCD = 4 bh x 8 q-tiles
    const int id = blockIdx.x;
    const int slot = id >> 3;                      // 0..31
    const int bh = ((id & 7) << 2) | (slot >> 3);
    const int qt = slot & 7;
    const int b = bh >> 3, h = bh & 7;
    const int q0 = qt * 256;
    const size_t tokbase = (size_t)b * SS;
    const int hoff = h * HD;

    // 2 q-fragments per wave: q rows q0 + w*32 + f*16 + c (same for both groups)
    bf16x8 qf[2][2];
    #pragma unroll
    for (int f = 0; f < 2; ++f) {
        const int myq = q0 + w * 32 + f * 16 + c;
        #pragma unroll
        for (int kt = 0; kt < 2; ++kt)
            qf[f][kt] = *(const bf16x8*)&q[(tokbase + myq) * EMB + hoff + kt * 32 + quad * 8];
    }

    union { u32 u[4]; bf16x8 v; } ones;
    #pragma unroll
    for (int i = 0; i < 4; ++i) ones.u[i] = 0x3F803F80u;   // bf16 1.0 pairs

    // staging: 512 threads per group x 16B = 8KB tile per buffer per group
    const int tig = tid & 511;
    const u16* kp; const u16* vp;
    {
        const int rr = tig >> 3, ch = (tig & 7) ^ (rr & 7);
        kp = k + (tokbase + g * 1024 + rr) * EMB + hoff + ch * 8;
        vp = vt + ((size_t)(b * NH + h) * HD + rr) * SS + g * 1024 + ch * 8;
    }
    auto stage = [&](int buf) {
        async16(kp, (char*)&sK[g][buf][0] + tig * 16);
        kp += 64 * EMB;
        async16(vp, (char*)&sV[g][buf][0] + tig * 16);
        vp += 64;
    };
    stage(0);

    f32x4 accO[2][4] = {};
    f32x4 accL[2] = {};
    const f32x4 zc = {};

#define ATTN_STEP(BUFC, DO_STAGE)                                              \
    {                                                                          \
        __syncthreads();                 /* drains stage for buffer BUFC */    \
        if (DO_STAGE) stage(BUFC ^ 1);                                         \
        f32x4 accS[2][4];                                                      \
        __builtin_amdgcn_s_setprio(1);                                         \
        _Pragma("unroll")                                                      \
        for (int mt = 0; mt < 4; ++mt) {                                       \
            const int key = mt * 16 + c;                                       \
            bf16x8 kf0 = *(const bf16x8*)&sK[g][BUFC][(key * 8 + (quad ^ (key & 7))) * 8]; \
            _Pragma("unroll")                                                  \
            for (int f = 0; f < 2; ++f)                                        \
                accS[f][mt] = mfma16(kf0, qf[f][0], zc);                       \
            bf16x8 kf1 = *(const bf16x8*)&sK[g][BUFC][(key * 8 + ((4 + quad) ^ (key & 7))) * 8]; \
            _Pragma("unroll")                                                  \
            for (int f = 0; f < 2; ++f)                                        \
                accS[f][mt] = mfma16(kf1, qf[f][1], accS[f][mt]);              \
        }                                                                      \
        __builtin_amdgcn_s_setprio(0);                                         \
        _Pragma("unroll")                                                      \
        for (int f = 0; f < 2; ++f) {                                          \
            u32 pw[8];                                                         \
            _Pragma("unroll")                                                  \
            for (int mt = 0; mt < 4; ++mt) {                                   \
                const float e0 = __builtin_amdgcn_exp2f(accS[f][mt][0]);       \
                const float e1 = __builtin_amdgcn_exp2f(accS[f][mt][1]);       \
                const float e2 = __builtin_amdgcn_exp2f(accS[f][mt][2]);       \
                const float e3 = __builtin_amdgcn_exp2f(accS[f][mt][3]);       \
                pw[2 * mt]     = __builtin_amdgcn_perm(__float_as_uint(e1), __float_as_uint(e0), 0x07060302u); \
                pw[2 * mt + 1] = __builtin_amdgcn_perm(__float_as_uint(e3), __float_as_uint(e2), 0x07060302u); \
            }                                                                  \
            _Pragma("unroll")                                                  \
            for (int mt = 0; mt < 4; ++mt) {                                   \
                const int chunkW = 2 * mt + (quad >> 1);                       \
                const int blk = c * 8 + (chunkW ^ (c & 7));                    \
                uint2 u; u.x = pw[2 * mt]; u.y = pw[2 * mt + 1];               \
                *(uint2*)((char*)&sP[w16 * 2 + f][0] + blk * 16 + 8 * (quad & 1)) = u; \
            }                                                                  \
        }                                                                      \
        bf16x8 pf[2][2];                                                       \
        _Pragma("unroll")                                                      \
        for (int f = 0; f < 2; ++f) {                                          \
            _Pragma("unroll")                                                  \
            for (int kt = 0; kt < 2; ++kt)                                     \
                pf[f][kt] = *(const bf16x8*)&sP[w16 * 2 + f][(c * 8 + ((kt * 4 + quad) ^ (c & 7))) * 8]; \
        }                                                                      \
        __builtin_amdgcn_s_setprio(1);                                         \
        _Pragma("unroll")                                                      \
        for (int f = 0; f < 2; ++f) {                                          \
            accL[f] = mfma16(ones.v, pf[f][0], accL[f]);                       \
            accL[f] = mfma16(ones.v, pf[f][1], accL[f]);                       \
        }                                                                      \
        _Pragma("unroll")                                                      \
        for (int nt = 0; nt < 4; ++nt) {                                       \
            const int d = nt * 16 + c;                                         \
            _Pragma("unroll")                                                  \
            for (int kt = 0; kt < 2; ++kt) {                                   \
                bf16x8 vf = *(const bf16x8*)&sV[g][BUFC][(d * 8 + ((kt * 4 + quad) ^ (d & 7))) * 8]; \
                _Pragma("unroll")                                              \
                for (int f = 0; f < 2; ++f)                                    \
                    accO[f][nt] = mfma16(vf, pf[f][kt], accO[f][nt]);          \
            }                                                                  \
        }                                                                      \
        __builtin_amdgcn_s_setprio(0);                                         \
    }

    // 16 iterations: 7 pairs + peeled last pair (final body has no prefetch)
    for (int tp = 0; tp < 7; ++tp) {
        ATTN_STEP(0, true);
        ATTN_STEP(1, true);
    }
    ATTN_STEP(0, true);
    ATTN_STEP(1, false);
#undef ATTN_STEP

    // ------- merge the two key-range halves through LDS (symmetric) -------
    __syncthreads();                      // all compute (incl. sP reads) done
    float* mb = (float*)&sP[0][0];        // 256 tok x 64 d f32 = 64 KB
    float* ml = (float*)&sK[0][0][0];     // 256 f32
    {
        // phase 1: export one fragment's partials (disjoint row sets per group)
        const int fe = g ^ 1;             // g0 exports f=1, g1 exports f=0
        const int mtok = w * 32 + fe * 16 + c;
        #pragma unroll
        for (int nt = 0; nt < 4; ++nt) {
            const int dcol = (nt * 16 + quad * 4) ^ ((mtok & 7) << 2);
            *(f32x4*)&mb[mtok * 64 + dcol] = accO[fe][nt];
        }
        if (quad == 0) ml[mtok] = accL[fe][0];
    }
    __syncthreads();
    {
        // phase 2: merge the other fragment; both groups store in parallel
        const int fm = g;                 // g0 merges f=0, g1 merges f=1
        const int mtok = w * 32 + fm * 16 + c;
        const float l = accL[fm][0] + ml[mtok];
        const float li = (l > 0.0f) ? (1.0f / l) : 0.0f;
        const int tok = q0 + mtok;
        u16* dst = ctx + (tokbase + tok) * EMB + hoff + quad * 4;
        #pragma unroll
        for (int nt = 0; nt < 4; ++nt) {
            const int dcol = (nt * 16 + quad * 4) ^ ((mtok & 7) << 2);
            const f32x4 pt = *(const f32x4*)&mb[mtok * 64 + dcol];
            ushort4 pk;
            pk.x = ftrunc_bf((accO[fm][nt][0] + pt[0]) * li);
            pk.y = ftrunc_bf((accO[fm][nt][1] + pt[1]) * li);
            pk.z = ftrunc_bf((accO[fm][nt][2] + pt[2]) * li);
            pk.w = ftrunc_bf((accO[fm][nt][3] + pt[3]) * li);
            *(ushort4*)&dst[nt * 16] = pk;
        }
    }
}

// ---------------------------------------------------------------------------
// Residual + LayerNorm over EMB=512, bf16 in, one wave per row.
// ---------------------------------------------------------------------------
__global__ __launch_bounds__(256) void ln_mid(
    const u16* __restrict__ a, const u16* __restrict__ b2,
    const float* __restrict__ g, const float* __restrict__ be,
    u16* __restrict__ outb)
{
    const int wave = threadIdx.x >> 6, lane = threadIdx.x & 63;
    const size_t row = (size_t)blockIdx.x * 4 + wave;
    const u16x8 av = *(const u16x8*)&a[row * EMB + lane * 8];
    const u16x8 bv = *(const u16x8*)&b2[row * EMB + lane * 8];
    float vals[8], sum = 0.0f;
    #pragma unroll
    for (int i = 0; i < 8; ++i) { vals[i] = bf2f(av[i]) + bf2f(bv[i]); sum += vals[i]; }
    #pragma unroll
    for (int o = 1; o < 64; o <<= 1) sum += __shfl_xor(sum, o);
    const float mu = sum * (1.0f / 512.0f);
    float vs = 0.0f;
    #pragma unroll
    for (int i = 0; i < 8; ++i) { const float d = vals[i] - mu; vs += d * d; }
    #pragma unroll
    for (int o = 1; o < 64; o <<= 1) vs += __shfl_xor(vs, o);
    const float rstd = rsqrtf(vs * (1.0f / 512.0f) + EPS);
    u16x8 ov;
    #pragma unroll
    for (int i = 0; i < 8; ++i) {
        const int col = lane * 8 + i;
        ov[i] = f2bf((vals[i] - mu) * rstd * g[col] + be[col]);
    }
    *(u16x8*)&outb[row * EMB + lane * 8] = ov;
}

__global__ __launch_bounds__(256) void ln_final(
    const u16* __restrict__ a, const u16* __restrict__ b2,
    const float* __restrict__ g, const float* __restrict__ be,
    void* __restrict__ dout, const u16* __restrict__ xsrc)
{
    const int isf = derive_flag(xsrc);
    const int wave = threadIdx.x >> 6, lane = threadIdx.x & 63;
    const size_t row = (size_t)blockIdx.x * 4 + wave;
    const u16x8 av = *(const u16x8*)&a[row * EMB + lane * 8];
    const u16x8 bv = *(const u16x8*)&b2[row * EMB + lane * 8];
    float vals[8], sum = 0.0f;
    #pragma unroll
    for (int i = 0; i < 8; ++i) { vals[i] = bf2f(av[i]) + bf2f(bv[i]); sum += vals[i]; }
    #pragma unroll
    for (int o = 1; o < 64; o <<= 1) sum += __shfl_xor(sum, o);
    const float mu = sum * (1.0f / 512.0f);
    float vs = 0.0f;
    #pragma unroll
    for (int i = 0; i < 8; ++i) { const float d = vals[i] - mu; vs += d * d; }
    #pragma unroll
    for (int o = 1; o < 64; o <<= 1) vs += __shfl_xor(vs, o);
    const float rstd = rsqrtf(vs * (1.0f / 512.0f) + EPS);
    if (isf) {
        #pragma unroll
        for (int i = 0; i < 8; ++i) {
            const int col = lane * 8 + i;
            ((float*)dout)[row * EMB + col] = (vals[i] - mu) * rstd * g[col] + be[col];
        }
    } else {
        u16x8 ov;
        #pragma unroll
        for (int i = 0; i < 8; ++i) {
            const int col = lane * 8 + i;
            ov[i] = f2bf((vals[i] - mu) * rstd * g[col] + be[col]);
        }
        *(u16x8*)&((u16*)dout)[row * EMB + lane * 8] = ov;
    }
}

// ---------------------------------------------------------------------------
extern "C" void kernel_launch(void* const* d_in, const int* in_sizes, int n_in,
                              void* d_out, int out_size, void* d_ws, size_t ws_size,
                              hipStream_t stream)
{
    char* ws = (char*)d_ws;
    float* small = (float*)(ws + 0);        // 7168 f32
    u16*   wt1   = (u16*)(ws + 32768);
    u16*   wt2   = (u16*)(ws + 819200);
    u16*   f1t   = (u16*)(ws + 2392064);
    u16*   f2t   = (u16*)(ws + 3440640);
    u16*   xbf   = (u16*)(ws + 4489216);
    u16*   h3    = (u16*)(ws + 8683520);    // [3][NT][512]; reused as h2 [NT][1024]
    u16*   qkv   = (u16*)(ws + 33849344);   // [3][NT][512] (v slot unused)
    u16*   vtb   = (u16*)(ws + 59015168);   // [B][H][64][S]
    u16*   ctxb  = (u16*)(ws + 67403776);
    u16*   x1b   = (u16*)(ws + 75792384);
    u16*   ffb   = (u16*)(ws + 84180992);

    const dim3 blk(256);
    const u16* xsrc = (const u16*)d_in[0];

    prep<<<dim3(32, 32, 10), blk, 0, stream>>>(
        xsrc,
        d_in[1], d_in[5], d_in[9], d_in[3], d_in[7], d_in[11], d_in[13], d_in[15],
        d_in[2], d_in[6], d_in[10], d_in[4], d_in[8], d_in[12],
        d_in[14], d_in[16], d_in[17], d_in[18], d_in[19], d_in[20],
        xbf, wt1, wt2, f1t, f2t, small);

    // qkv layer 1: h3[which] = relu(x @ W1 + b1)   grid (rowtiles, which*ctiles)
    gemm64<true, false, false, false><<<dim3(128, 24), blk, 0, stream>>>(
        xbf, wt1, small + 0, h3, nullptr, NT, INF_, EMB);
    // qkv layer 2: q -> qkv[0]; k*C2 -> qkv[1]; v -> vtb (transposed)
    gemm64<false, true, true, true><<<dim3(128, 24), blk, 0, stream>>>(
        h3, wt2, small + 1536, qkv, vtb, NT, EMB, EMB);

    attn_mfma<<<dim3(256), dim3(1024), 0, stream>>>(
        qkv, qkv + (size_t)NT * EMB, vtb, ctxb);

    // x1 = LN(ctx + q)
    ln_mid<<<NT / 4, blk, 0, stream>>>(ctxb, qkv, small + 4608, small + 5120, x1b);

    // FFN
    u16* h2 = h3;
    gemm64<true, false, false, false><<<dim3(128, 16), blk, 0, stream>>>(
        x1b, f1t, small + 3072, h2, nullptr, NT, EMB, 1024);
    gemm64<false, false, false, false><<<dim3(128, 8), blk, 0, stream>>>(
        h2, f2t, small + 4096, ffb, nullptr, NT, 1024, EMB);

    // out = LN(x1 + ff)
    ln_final<<<NT / 4, blk, 0, stream>>>(x1b, ffb, small + 5632, small + 6144, d_out, xsrc);
}

// Round 14
// 222.915 us; speedup vs baseline: 1.0747x; 1.0747x over previous
//
#include <hip/hip_runtime.h>
#include <hip/hip_bf16.h>
#include <math.h>

#define BB   4
#define SS   2048
#define INF_ 256
#define EMB  512
#define NH   8
#define HD   64
#define NT   8192

typedef unsigned short u16;
typedef unsigned int   u32;
typedef __attribute__((ext_vector_type(8))) short bf16x8;   // 8 bf16 = 4 VGPRs
typedef __attribute__((ext_vector_type(8))) unsigned short u16x8;
typedef __attribute__((ext_vector_type(4))) float f32x4;

constexpr float C2  = 0.06375871607f;    // (1/sqrt(512)) * log2(e)
constexpr float TB  = 1.00390625f;       // 1 + 2^-8
constexpr float EPS = 1e-5f;

__device__ __forceinline__ u16 f2bf(float v) {
    __hip_bfloat16 h = __float2bfloat16(v);
    return *(u16*)&h;
}
__device__ __forceinline__ float bf2f(u16 u) {
    __hip_bfloat16 h = *(__hip_bfloat16*)&u;
    return __bfloat162float(h);
}
__device__ __forceinline__ u16 ftrunc_bf(float v) {     // trunc + half-ulp bias
    return (u16)(__float_as_uint(v * TB) >> 16);
}
__device__ __forceinline__ f32x4 mfma16(bf16x8 a, bf16x8 b, f32x4 c) {
    return __builtin_amdgcn_mfma_f32_16x16x32_bf16(a, b, c, 0, 0, 0);
}
__device__ __forceinline__ void async16(const void* g, void* l) {
    __builtin_amdgcn_global_load_lds(
        (const __attribute__((address_space(1))) void*)g,
        (__attribute__((address_space(3))) void*)l, 16, 0, 0);
}
__device__ __forceinline__ int derive_flag(const u16* x) {
    const int lane = threadIdx.x & 63;
    const unsigned e = (x[lane * 2] >> 7) & 0xFF;
    float pl = (e == 0 || (e >= 110 && e <= 140)) ? 1.0f : 0.0f;
    #pragma unroll
    for (int o = 1; o < 64; o <<= 1) pl += __shfl_xor(pl, o);
    return pl < 32.0f;
}

// ---------------------------------------------------------------------------
// Fused prep: z 0..7 weight transpose W[K][M]->Wt[M][K] bf16; z=8 x->bf16;
// z=9 biases/ln params -> packed f32.
// ---------------------------------------------------------------------------
__global__ __launch_bounds__(256) void prep(
    const u16* __restrict__ xsrc,
    const void* w0, const void* w1, const void* w2, const void* w3,
    const void* w4, const void* w5, const void* w6, const void* w7,
    const void* p0, const void* p1, const void* p2, const void* p3,
    const void* p4, const void* p5, const void* p6, const void* p7,
    const void* p8, const void* p9, const void* p10, const void* p11,
    u16* __restrict__ xbf, u16* __restrict__ wt1, u16* __restrict__ wt2,
    u16* __restrict__ f1t, u16* __restrict__ f2t, float* __restrict__ small)
{
    const int isf = derive_flag(xsrc);
    const int z = blockIdx.z;
    const int tid = threadIdx.x;

    if (z < 8) {
        int K, M; const void* src; u16* dst;
        switch (z) {
            case 0: K=256;  M=512;  src=w0; dst=wt1;             break;
            case 1: K=256;  M=512;  src=w1; dst=wt1+512*256;     break;
            case 2: K=256;  M=512;  src=w2; dst=wt1+2*512*256;   break;
            case 3: K=512;  M=512;  src=w3; dst=wt2;             break;
            case 4: K=512;  M=512;  src=w4; dst=wt2+512*512;     break;
            case 5: K=512;  M=512;  src=w5; dst=wt2+2*512*512;   break;
            case 6: K=512;  M=1024; src=w6; dst=f1t;             break;
            default:K=1024; M=512;  src=w7; dst=f2t;             break;
        }
        const int m0 = blockIdx.x * 32, k0 = blockIdx.y * 32;
        if (m0 >= M || k0 >= K) return;
        __shared__ u16 t[32][33];
        const int tx = tid & 31, ty = tid >> 5;
        #pragma unroll
        for (int i = 0; i < 4; ++i) {
            const int kk = k0 + ty + i * 8;
            t[ty + i * 8][tx] = isf ? ftrunc_bf(((const float*)src)[(size_t)kk * M + m0 + tx])
                                    : ((const u16*)src)[(size_t)kk * M + m0 + tx];
        }
        __syncthreads();
        #pragma unroll
        for (int i = 0; i < 4; ++i) {
            const int mm = m0 + ty + i * 8;
            dst[(size_t)mm * K + k0 + tx] = t[tx][ty + i * 8];
        }
    } else if (z == 8) {
        const int bid = blockIdx.y * 32 + blockIdx.x;    // 0..1023
        const int base = bid * 2048 + tid * 8;
        if (isf) {
            #pragma unroll
            for (int j = 0; j < 8; ++j)
                xbf[base + j] = ftrunc_bf(((const float*)xsrc)[base + j]);
        } else {
            *(u16x8*)&xbf[base] = *(const u16x8*)&xsrc[base];
        }
    } else {
        const int bid = blockIdx.y * 32 + blockIdx.x;
        if (bid >= 28) return;
        const int e = bid * 256 + tid;
        int id, i;
        if (e < 3072)      { id = e >> 9;               i = e & 511;          }
        else if (e < 4096) { id = 6;                    i = e - 3072;         }
        else               { id = 7 + ((e - 4096) >> 9); i = (e - 4096) & 511; }
        const void* src;
        switch (id) {
            case 0: src = p0; break;  case 1: src = p1; break;
            case 2: src = p2; break;  case 3: src = p3; break;
            case 4: src = p4; break;  case 5: src = p5; break;
            case 6: src = p6; break;  case 7: src = p7; break;
            case 8: src = p8; break;  case 9: src = p9; break;
            case 10: src = p10; break; default: src = p11; break;
        }
        small[e] = isf ? ((const float*)src)[i] : bf2f(((const u16*)src)[i]);
    }
}

// ---------------------------------------------------------------------------
// MFMA GEMM, 64x64 tile (8 blocks/CU for latency hiding on short-K loops).
// Grid: x = row-tile (XCD-aligned A reuse), y = which*(M/64) + col-tile.
// 4 waves, each 32x32 (2x2 fragments). BK=64, XOR-swizzled LDS, w=16 async.
// SCALEK: which==1 output scaled by C2 (k only feeds attention).
// VOUT: which==2 written transposed to [B][H][HD][S] via LDS.
// Epilogue routes acc through LDS so global stores are u16x8-coalesced.
// ---------------------------------------------------------------------------
template <bool RELU, bool AWHICH, bool VOUT, bool SCALEK>
__global__ __launch_bounds__(256) void gemm64(
    const u16* __restrict__ Aall, const u16* __restrict__ Wtall,
    const float* __restrict__ ball, u16* __restrict__ out,
    u16* __restrict__ vtb, int N, int K, int M)
{
    __shared__ __align__(16) u16 sA[64 * 64];   // 8 KB
    __shared__ __align__(16) u16 sB[64 * 64];   // 8 KB (also epilogue spill)

    const int mtiles = M >> 6;
    const int which = blockIdx.y / mtiles;
    const int colb  = blockIdx.y % mtiles;
    const int row0 = blockIdx.x << 6, col0 = colb << 6;
    const u16* A  = Aall + (AWHICH ? (size_t)which * N * K : 0);
    const u16* Wt = Wtall + (size_t)which * M * K;
    const float* bias = ball + (size_t)which * M;

    const int tid = threadIdx.x;
    const int lane = tid & 63, w = tid >> 6;
    const int wrow = (w & 1) << 5, wcol = (w >> 1) << 5;
    const int c = lane & 15, quad = lane >> 4;

    const u16* ap[2]; const u16* bp[2];
    #pragma unroll
    for (int i = 0; i < 2; ++i) {
        const int raw = i * 256 + tid, r = raw >> 3, ch = (raw & 7) ^ (r & 7);
        ap[i] = A + (size_t)(row0 + r) * K + ch * 8;
        bp[i] = Wt + (size_t)(col0 + r) * K + ch * 8;
    }

    f32x4 acc[2][2] = {};

    for (int k0 = 0; k0 < K; k0 += 64) {
        __syncthreads();
        #pragma unroll
        for (int i = 0; i < 2; ++i) {
            async16(ap[i], (char*)sA + (i * 256 + tid) * 16);
            ap[i] += 64;
            async16(bp[i], (char*)sB + (i * 256 + tid) * 16);
            bp[i] += 64;
        }
        __syncthreads();

        #pragma unroll
        for (int kt = 0; kt < 2; ++kt) {
            bf16x8 af[2], bfr[2];
            #pragma unroll
            for (int rt = 0; rt < 2; ++rt) {
                const int r = wrow + rt * 16 + c;
                af[rt] = *(const bf16x8*)&sA[(r * 8 + ((kt * 4 + quad) ^ (r & 7))) * 8];
            }
            #pragma unroll
            for (int ct = 0; ct < 2; ++ct) {
                const int r = wcol + ct * 16 + c;
                bfr[ct] = *(const bf16x8*)&sB[(r * 8 + ((kt * 4 + quad) ^ (r & 7))) * 8];
            }
            #pragma unroll
            for (int rt = 0; rt < 2; ++rt)
                #pragma unroll
                for (int ct = 0; ct < 2; ++ct)
                    acc[rt][ct] = mfma16(af[rt], bfr[ct], acc[rt][ct]);
        }
    }

    if (VOUT && which == 2) {
        // transpose through LDS: sA[col][row], stride 72 (144B rows, 16B-aligned)
        __syncthreads();
        #pragma unroll
        for (int rt = 0; rt < 2; ++rt) {
            const int rowb = wrow + rt * 16 + quad * 4;
            #pragma unroll
            for (int ct = 0; ct < 2; ++ct) {
                const int col = wcol + ct * 16 + c;
                const float bb = bias[col0 + col];
                ushort4 pk;
                pk.x = ftrunc_bf(acc[rt][ct][0] + bb);
                pk.y = ftrunc_bf(acc[rt][ct][1] + bb);
                pk.z = ftrunc_bf(acc[rt][ct][2] + bb);
                pk.w = ftrunc_bf(acc[rt][ct][3] + bb);
                *(ushort4*)&sA[col * 72 + rowb] = pk;
            }
        }
        __syncthreads();
        const int dl = tid >> 2, part = tid & 3;         // 64 cols x 4 row-parts
        const int hg = (col0 + dl) >> 6, dd = (col0 + dl) & 63;
        const int bb = row0 >> 11, s0 = row0 & 2047;
        u16* dst = vtb + ((size_t)(bb * NH + hg) * HD + dd) * SS + s0 + part * 16;
        #pragma unroll
        for (int j = 0; j < 2; ++j)
            *(u16x8*)&dst[j * 8] = *(const u16x8*)&sA[dl * 72 + part * 16 + j * 8];
        return;
    }

    // row-major epilogue through LDS: sA[row][col], stride 72, then
    // u16x8-coalesced stores (128B per wave instead of 4x32B scatter).
    const float sc = (SCALEK && which == 1) ? C2 : 1.0f;
    const size_t outW = (size_t)which * N * M;
    __syncthreads();
    #pragma unroll
    for (int rt = 0; rt < 2; ++rt) {
        #pragma unroll
        for (int ct = 0; ct < 2; ++ct) {
            const int col = wcol + ct * 16 + c;
            const float bb = bias[col0 + col];
            #pragma unroll
            for (int i = 0; i < 4; ++i) {
                const int row = wrow + rt * 16 + quad * 4 + i;
                float v = (acc[rt][ct][i] + bb) * sc;
                if (RELU) v = fmaxf(v, 0.0f);
                sA[row * 72 + col] = ftrunc_bf(v);
            }
        }
    }
    __syncthreads();
    const int dl = tid >> 2, part = tid & 3;             // 64 rows x 4 col-parts
    u16* dst = out + outW + (size_t)(row0 + dl) * M + col0 + part * 16;
    #pragma unroll
    for (int j = 0; j < 2; ++j)
        *(u16x8*)&dst[j * 8] = *(const u16x8*)&sA[dl * 72 + part * 16 + j * 8];
}

// ---------------------------------------------------------------------------
// MFMA flash attention, in-block 2-way K-split + s_setprio (R8 structure),
// pairwise-unrolled main loop (R12). Symmetric merge with STATIC fragment
// indices (R13's runtime accO[g^1] indexing demoted the accumulators to
// scratch — rule #20; fixed via wave-uniform branch + literal-index macro).
// ---------------------------------------------------------------------------
__global__ __launch_bounds__(1024) void attn_mfma(
    const u16* __restrict__ q, const u16* __restrict__ k,
    const u16* __restrict__ vt, u16* __restrict__ ctx)
{
    __shared__ __align__(16) u16 sK[2][2][4096];   // [group][buf][64x64] 32 KB
    __shared__ __align__(16) u16 sV[2][2][4096];   // 32 KB
    __shared__ __align__(16) u16 sP[32][1024];     // [wave*2+frag][16x64] 64 KB

    const int tid = threadIdx.x;
    const int w16 = tid >> 6, lane = tid & 63;
    const int g = w16 >> 3, w = w16 & 7;           // group, wave-in-group
    const int c = lane & 15, quad = lane >> 4;
    // XCD swizzle: id&7 = xcd; 32 slots/XCD = 4 bh x 8 q-tiles
    const int id = blockIdx.x;
    const int slot = id >> 3;                      // 0..31
    const int bh = ((id & 7) << 2) | (slot >> 3);
    const int qt = slot & 7;
    const int b = bh >> 3, h = bh & 7;
    const int q0 = qt * 256;
    const size_t tokbase = (size_t)b * SS;
    const int hoff = h * HD;

    // 2 q-fragments per wave: q rows q0 + w*32 + f*16 + c (same for both groups)
    bf16x8 qf[2][2];
    #pragma unroll
    for (int f = 0; f < 2; ++f) {
        const int myq = q0 + w * 32 + f * 16 + c;
        #pragma unroll
        for (int kt = 0; kt < 2; ++kt)
            qf[f][kt] = *(const bf16x8*)&q[(tokbase + myq) * EMB + hoff + kt * 32 + quad * 8];
    }

    union { u32 u[4]; bf16x8 v; } ones;
    #pragma unroll
    for (int i = 0; i < 4; ++i) ones.u[i] = 0x3F803F80u;   // bf16 1.0 pairs

    // staging: 512 threads per group x 16B = 8KB tile per buffer per group
    const int tig = tid & 511;
    const u16* kp; const u16* vp;
    {
        const int rr = tig >> 3, ch = (tig & 7) ^ (rr & 7);
        kp = k + (tokbase + g * 1024 + rr) * EMB + hoff + ch * 8;
        vp = vt + ((size_t)(b * NH + h) * HD + rr) * SS + g * 1024 + ch * 8;
    }
    auto stage = [&](int buf) {
        async16(kp, (char*)&sK[g][buf][0] + tig * 16);
        kp += 64 * EMB;
        async16(vp, (char*)&sV[g][buf][0] + tig * 16);
        vp += 64;
    };
    stage(0);

    f32x4 accO[2][4] = {};
    f32x4 accL[2] = {};
    const f32x4 zc = {};

#define ATTN_STEP(BUFC, DO_STAGE)                                              \
    {                                                                          \
        __syncthreads();                 /* drains stage for buffer BUFC */    \
        if (DO_STAGE) stage(BUFC ^ 1);                                         \
        f32x4 accS[2][4];                                                      \
        __builtin_amdgcn_s_setprio(1);                                         \
        _Pragma("unroll")                                                      \
        for (int mt = 0; mt < 4; ++mt) {                                       \
            const int key = mt * 16 + c;                                       \
            bf16x8 kf0 = *(const bf16x8*)&sK[g][BUFC][(key * 8 + (quad ^ (key & 7))) * 8]; \
            _Pragma("unroll")                                                  \
            for (int f = 0; f < 2; ++f)                                        \
                accS[f][mt] = mfma16(kf0, qf[f][0], zc);                       \
            bf16x8 kf1 = *(const bf16x8*)&sK[g][BUFC][(key * 8 + ((4 + quad) ^ (key & 7))) * 8]; \
            _Pragma("unroll")                                                  \
            for (int f = 0; f < 2; ++f)                                        \
                accS[f][mt] = mfma16(kf1, qf[f][1], accS[f][mt]);              \
        }                                                                      \
        __builtin_amdgcn_s_setprio(0);                                         \
        _Pragma("unroll")                                                      \
        for (int f = 0; f < 2; ++f) {                                          \
            u32 pw[8];                                                         \
            _Pragma("unroll")                                                  \
            for (int mt = 0; mt < 4; ++mt) {                                   \
                const float e0 = __builtin_amdgcn_exp2f(accS[f][mt][0]);       \
                const float e1 = __builtin_amdgcn_exp2f(accS[f][mt][1]);       \
                const float e2 = __builtin_amdgcn_exp2f(accS[f][mt][2]);       \
                const float e3 = __builtin_amdgcn_exp2f(accS[f][mt][3]);       \
                pw[2 * mt]     = __builtin_amdgcn_perm(__float_as_uint(e1), __float_as_uint(e0), 0x07060302u); \
                pw[2 * mt + 1] = __builtin_amdgcn_perm(__float_as_uint(e3), __float_as_uint(e2), 0x07060302u); \
            }                                                                  \
            _Pragma("unroll")                                                  \
            for (int mt = 0; mt < 4; ++mt) {                                   \
                const int chunkW = 2 * mt + (quad >> 1);                       \
                const int blk = c * 8 + (chunkW ^ (c & 7));                    \
                uint2 u; u.x = pw[2 * mt]; u.y = pw[2 * mt + 1];               \
                *(uint2*)((char*)&sP[w16 * 2 + f][0] + blk * 16 + 8 * (quad & 1)) = u; \
            }                                                                  \
        }                                                                      \
        bf16x8 pf[2][2];                                                       \
        _Pragma("unroll")                                                      \
        for (int f = 0; f < 2; ++f) {                                          \
            _Pragma("unroll")                                                  \
            for (int kt = 0; kt < 2; ++kt)                                     \
                pf[f][kt] = *(const bf16x8*)&sP[w16 * 2 + f][(c * 8 + ((kt * 4 + quad) ^ (c & 7))) * 8]; \
        }                                                                      \
        __builtin_amdgcn_s_setprio(1);                                         \
        _Pragma("unroll")                                                      \
        for (int f = 0; f < 2; ++f) {                                          \
            accL[f] = mfma16(ones.v, pf[f][0], accL[f]);                       \
            accL[f] = mfma16(ones.v, pf[f][1], accL[f]);                       \
        }                                                                      \
        _Pragma("unroll")                                                      \
        for (int nt = 0; nt < 4; ++nt) {                                       \
            const int d = nt * 16 + c;                                         \
            _Pragma("unroll")                                                  \
            for (int kt = 0; kt < 2; ++kt) {                                   \
                bf16x8 vf = *(const bf16x8*)&sV[g][BUFC][(d * 8 + ((kt * 4 + quad) ^ (d & 7))) * 8]; \
                _Pragma("unroll")                                              \
                for (int f = 0; f < 2; ++f)                                    \
                    accO[f][nt] = mfma16(vf, pf[f][kt], accO[f][nt]);          \
            }                                                                  \
        }                                                                      \
        __builtin_amdgcn_s_setprio(0);                                         \
    }

    // 16 iterations: 7 pairs + peeled last pair (final body has no prefetch)
    for (int tp = 0; tp < 7; ++tp) {
        ATTN_STEP(0, true);
        ATTN_STEP(1, true);
    }
    ATTN_STEP(0, true);
    ATTN_STEP(1, false);
#undef ATTN_STEP

    // ------- merge the two key-range halves through LDS (symmetric, -------
    // ------- STATIC fragment indices: wave-uniform branch on g)      -------
    __syncthreads();                      // all compute (incl. sP reads) done
    float* mb = (float*)&sP[0][0];        // 256 tok x 64 d f32 = 64 KB
    float* ml = (float*)&sK[0][0][0];     // 256 f32

#define EXPORT_FRAG(FE)                                                        \
    {                                                                          \
        const int mtok = w * 32 + (FE) * 16 + c;                               \
        _Pragma("unroll")                                                      \
        for (int nt = 0; nt < 4; ++nt) {                                       \
            const int dcol = (nt * 16 + quad * 4) ^ ((mtok & 7) << 2);         \
            *(f32x4*)&mb[mtok * 64 + dcol] = accO[FE][nt];                     \
        }                                                                      \
        if (quad == 0) ml[mtok] = accL[FE][0];                                 \
    }
#define MERGE_FRAG(FM)                                                         \
    {                                                                          \
        const int mtok = w * 32 + (FM) * 16 + c;                               \
        const float l = accL[FM][0] + ml[mtok];                                \
        const float li = (l > 0.0f) ? (1.0f / l) : 0.0f;                       \
        const int tok = q0 + mtok;                                             \
        u16* dst = ctx + (tokbase + tok) * EMB + hoff + quad * 4;              \
        _Pragma("unroll")                                                      \
        for (int nt = 0; nt < 4; ++nt) {                                       \
            const int dcol = (nt * 16 + quad * 4) ^ ((mtok & 7) << 2);         \
            const f32x4 pt = *(const f32x4*)&mb[mtok * 64 + dcol];             \
            ushort4 pk;                                                        \
            pk.x = ftrunc_bf((accO[FM][nt][0] + pt[0]) * li);                  \
            pk.y = ftrunc_bf((accO[FM][nt][1] + pt[1]) * li);                  \
            pk.z = ftrunc_bf((accO[FM][nt][2] + pt[2]) * li);                  \
            pk.w = ftrunc_bf((accO[FM][nt][3] + pt[3]) * li);                  \
            *(ushort4*)&dst[nt * 16] = pk;                                     \
        }                                                                      \
    }

    // g0 exports f=1, g1 exports f=0 (disjoint token rows)
    if (g == 0) EXPORT_FRAG(1) else EXPORT_FRAG(0)
    __syncthreads();
    // g0 merges f=0, g1 merges f=1 — all 16 waves store in parallel
    if (g == 0) MERGE_FRAG(0) else MERGE_FRAG(1)
#undef EXPORT_FRAG
#undef MERGE_FRAG
}

// ---------------------------------------------------------------------------
// Residual + LayerNorm over EMB=512, bf16 in, one wave per row.
// ---------------------------------------------------------------------------
__global__ __launch_bounds__(256) void ln_mid(
    const u16* __restrict__ a, const u16* __restrict__ b2,
    const float* __restrict__ g, const float* __restrict__ be,
    u16* __restrict__ outb)
{
    const int wave = threadIdx.x >> 6, lane = threadIdx.x & 63;
    const size_t row = (size_t)blockIdx.x * 4 + wave;
    const u16x8 av = *(const u16x8*)&a[row * EMB + lane * 8];
    const u16x8 bv = *(const u16x8*)&b2[row * EMB + lane * 8];
    float vals[8], sum = 0.0f;
    #pragma unroll
    for (int i = 0; i < 8; ++i) { vals[i] = bf2f(av[i]) + bf2f(bv[i]); sum += vals[i]; }
    #pragma unroll
    for (int o = 1; o < 64; o <<= 1) sum += __shfl_xor(sum, o);
    const float mu = sum * (1.0f / 512.0f);
    float vs = 0.0f;
    #pragma unroll
    for (int i = 0; i < 8; ++i) { const float d = vals[i] - mu; vs += d * d; }
    #pragma unroll
    for (int o = 1; o < 64; o <<= 1) vs += __shfl_xor(vs, o);
    const float rstd = rsqrtf(vs * (1.0f / 512.0f) + EPS);
    u16x8 ov;
    #pragma unroll
    for (int i = 0; i < 8; ++i) {
        const int col = lane * 8 + i;
        ov[i] = f2bf((vals[i] - mu) * rstd * g[col] + be[col]);
    }
    *(u16x8*)&outb[row * EMB + lane * 8] = ov;
}

__global__ __launch_bounds__(256) void ln_final(
    const u16* __restrict__ a, const u16* __restrict__ b2,
    const float* __restrict__ g, const float* __restrict__ be,
    void* __restrict__ dout, const u16* __restrict__ xsrc)
{
    const int isf = derive_flag(xsrc);
    const int wave = threadIdx.x >> 6, lane = threadIdx.x & 63;
    const size_t row = (size_t)blockIdx.x * 4 + wave;
    const u16x8 av = *(const u16x8*)&a[row * EMB + lane * 8];
    const u16x8 bv = *(const u16x8*)&b2[row * EMB + lane * 8];
    float vals[8], sum = 0.0f;
    #pragma unroll
    for (int i = 0; i < 8; ++i) { vals[i] = bf2f(av[i]) + bf2f(bv[i]); sum += vals[i]; }
    #pragma unroll
    for (int o = 1; o < 64; o <<= 1) sum += __shfl_xor(sum, o);
    const float mu = sum * (1.0f / 512.0f);
    float vs = 0.0f;
    #pragma unroll
    for (int i = 0; i < 8; ++i) { const float d = vals[i] - mu; vs += d * d; }
    #pragma unroll
    for (int o = 1; o < 64; o <<= 1) vs += __shfl_xor(vs, o);
    const float rstd = rsqrtf(vs * (1.0f / 512.0f) + EPS);
    if (isf) {
        #pragma unroll
        for (int i = 0; i < 8; ++i) {
            const int col = lane * 8 + i;
            ((float*)dout)[row * EMB + col] = (vals[i] - mu) * rstd * g[col] + be[col];
        }
    } else {
        u16x8 ov;
        #pragma unroll
        for (int i = 0; i < 8; ++i) {
            const int col = lane * 8 + i;
            ov[i] = f2bf((vals[i] - mu) * rstd * g[col] + be[col]);
        }
        *(u16x8*)&((u16*)dout)[row * EMB + lane * 8] = ov;
    }
}

// ---------------------------------------------------------------------------
extern "C" void kernel_launch(void* const* d_in, const int* in_sizes, int n_in,
                              void* d_out, int out_size, void* d_ws, size_t ws_size,
                              hipStream_t stream)
{
    char* ws = (char*)d_ws;
    float* small = (float*)(ws + 0);        // 7168 f32
    u16*   wt1   = (u16*)(ws + 32768);
    u16*   wt2   = (u16*)(ws + 819200);
    u16*   f1t   = (u16*)(ws + 2392064);
    u16*   f2t   = (u16*)(ws + 3440640);
    u16*   xbf   = (u16*)(ws + 4489216);
    u16*   h3    = (u16*)(ws + 8683520);    // [3][NT][512]; reused as h2 [NT][1024]
    u16*   qkv   = (u16*)(ws + 33849344);   // [3][NT][512] (v slot unused)
    u16*   vtb   = (u16*)(ws + 59015168);   // [B][H][64][S]
    u16*   ctxb  = (u16*)(ws + 67403776);
    u16*   x1b   = (u16*)(ws + 75792384);
    u16*   ffb   = (u16*)(ws + 84180992);

    const dim3 blk(256);
    const u16* xsrc = (const u16*)d_in[0];

    prep<<<dim3(32, 32, 10), blk, 0, stream>>>(
        xsrc,
        d_in[1], d_in[5], d_in[9], d_in[3], d_in[7], d_in[11], d_in[13], d_in[15],
        d_in[2], d_in[6], d_in[10], d_in[4], d_in[8], d_in[12],
        d_in[14], d_in[16], d_in[17], d_in[18], d_in[19], d_in[20],
        xbf, wt1, wt2, f1t, f2t, small);

    // qkv layer 1: h3[which] = relu(x @ W1 + b1)   grid (rowtiles, which*ctiles)
    gemm64<true, false, false, false><<<dim3(128, 24), blk, 0, stream>>>(
        xbf, wt1, small + 0, h3, nullptr, NT, INF_, EMB);
    // qkv layer 2: q -> qkv[0]; k*C2 -> qkv[1]; v -> vtb (transposed)
    gemm64<false, true, true, true><<<dim3(128, 24), blk, 0, stream>>>(
        h3, wt2, small + 1536, qkv, vtb, NT, EMB, EMB);

    attn_mfma<<<dim3(256), dim3(1024), 0, stream>>>(
        qkv, qkv + (size_t)NT * EMB, vtb, ctxb);

    // x1 = LN(ctx + q)
    ln_mid<<<NT / 4, blk, 0, stream>>>(ctxb, qkv, small + 4608, small + 5120, x1b);

    // FFN
    u16* h2 = h3;
    gemm64<true, false, false, false><<<dim3(128, 16), blk, 0, stream>>>(
        x1b, f1t, small + 3072, h2, nullptr, NT, EMB, 1024);
    gemm64<false, false, false, false><<<dim3(128, 8), blk, 0, stream>>>(
        h2, f2t, small + 4096, ffb, nullptr, NT, 1024, EMB);

    // out = LN(x1 + ff)
    ln_final<<<NT / 4, blk, 0, stream>>>(x1b, ffb, small + 5632, small + 6144, d_out, xsrc);
}